// Round 9
// baseline (2056.323 us; speedup 1.0000x reference)
//
#include <hip/hip_runtime.h>
#include <hip/hip_bf16.h>
#include <hip/hip_fp8.h>

#define NU_ 100000
#define NT_ 200000
#define NE_ 1000000
#define HD  64
#define NL  3

// hist/dinv region offsets (node-keyed arrays)
#define OFF0 0                   // u2u dst (NU)  [selfloop]
#define OFF1 (NU_)               // t2t dst (NT)  [selfloop]
#define OFF2 (NU_ + NT_)         // u2t dst (NT)
#define OFF3 (NU_ + 2 * NT_)     // t2u dst (NU)
#define OFF4 (2 * NU_ + 2 * NT_) // u2t src (NU)
#define OFF5 (3 * NU_ + 2 * NT_) // t2u src (NT)
#define HTOT (3 * NU_ + 3 * NT_) // 900k
#define RPT2 (NU_ + NT_)         // merged rp/fill size (300k)

// merged scan partition (256/block)
#define NBU 391
#define NBT 782
#define NBTOT2 (NBU + NBT)

// fused grids
#define HB  23438          // ceil(6M/256) hist blocks
#define EU  4096           // embed user blocks
#define ET  8192           // embed txn blocks
#define PB  15625          // ceil(4M/256) place blocks
#define SG1 2048           // single-gemm user segment blocks (x2)
#define SG2 4096           // single-gemm txn segment blocks (x2)
#define GU  4096           // gemm_dual user blocks
#define GT  8192           // gemm_dual txn blocks
#define GBU 25000          // ceil(NU/4) gather blocks (user)
#define GBT 50000          // ceil(NT/4) gather blocks (txn)

typedef float floatx2 __attribute__((ext_vector_type(2)));

// ---------------- fp8 helpers ----------------
__device__ __forceinline__ unsigned char enc_fp8(float v) {
    return (unsigned char)__hip_cvt_float_to_fp8(v, __HIP_SATFINITE, __HIP_E4M3);
}

__device__ __forceinline__ float dec1_fp8(unsigned int u) {
    int e = (u >> 3) & 15;
    int m = u & 7;
    int mant = m | (e ? 8 : 0);
    if (u & 0x80) mant = -mant;
    int ex = (e ? e : 1) - 10;
    return (float)mant * __uint_as_float((unsigned int)(ex + 127) << 23);
}

__device__ __forceinline__ void dec4_fp8(unsigned int u, float* f) {
#if __has_builtin(__builtin_amdgcn_cvt_pk_f32_fp8)
    floatx2 lo = __builtin_amdgcn_cvt_pk_f32_fp8((int)u, false);
    floatx2 hi = __builtin_amdgcn_cvt_pk_f32_fp8((int)u, true);
    f[0] = lo.x; f[1] = lo.y; f[2] = hi.x; f[3] = hi.y;
#else
    f[0] = dec1_fp8(u & 0xff);
    f[1] = dec1_fp8((u >> 8) & 0xff);
    f[2] = dec1_fp8((u >> 16) & 0xff);
    f[3] = dec1_fp8((u >> 24) & 0xff);
#endif
}

// ---------------- dtype detection ----------------
__global__ void detect_dtype(const unsigned short* __restrict__ x, int* __restrict__ flag, int n) {
    __shared__ int s_big;
    if (threadIdx.x == 0) s_big = 0;
    __syncthreads();
    int big = 0;
    for (int i = threadIdx.x; i < n; i += blockDim.x) {
        float v = __uint_as_float(((unsigned int)x[i]) << 16);
        if (!(fabsf(v) < 1.0e4f)) big = 1;
    }
    if (big) atomicAdd(&s_big, 1);
    __syncthreads();
    if (threadIdx.x == 0) flag[0] = (s_big > 0) ? 0 : 1;
}

// ---------------- fused weight conversion (+ gsum zero) ----------------
struct Ptr10 { const void* p[10]; };

__global__ void cvt_weights(Ptr10 src, float* __restrict__ dst, float* __restrict__ gsum,
                            const int* __restrict__ flag) {
    const int c[11] = {0, 2048, 2112, 6208, 6272, 55424, 56192, 60288, 60352, 60416, 60417};
    int i = blockIdx.x * blockDim.x + threadIdx.x;
    if (i < 64) gsum[i] = 0.f;
    if (i >= 60417) return;
    int r = 0;
#pragma unroll
    for (int k = 1; k < 10; ++k)
        if (i >= c[k]) r = k;
    int e = i - c[r];
    if (flag[0]) {
        unsigned short u = ((const unsigned short*)src.p[r])[e];
        dst[i] = __uint_as_float(((unsigned int)u) << 16);
    } else {
        dst[i] = ((const float*)src.p[r])[e];
    }
}

// ---------------- device bodies ----------------
__device__ __forceinline__ void hist_dev(int gid, const int* __restrict__ a0,
                                         const int* __restrict__ a1, const int* __restrict__ a2,
                                         const int* __restrict__ a3, const int* __restrict__ a4,
                                         const int* __restrict__ a5, int* __restrict__ hist) {
    if (gid >= 6 * NE_) return;
    int r = gid / NE_;
    int e = gid - r * NE_;
    const int* a;
    int base;
    switch (r) {
        case 0: a = a0; base = OFF0; break;
        case 1: a = a1; base = OFF1; break;
        case 2: a = a2; base = OFF2; break;
        case 3: a = a3; base = OFF3; break;
        case 4: a = a4; base = OFF4; break;
        default: a = a5; base = OFF5; break;
    }
    atomicAdd(&hist[base + a[e]], 1);
}

template <int K>
__device__ __forceinline__ void embed_dev(int bid, int nblk, const void* __restrict__ x,
                                          const float* __restrict__ W,
                                          const float* __restrict__ bias,
                                          float* __restrict__ out, int N,
                                          const int* __restrict__ flag) {
    const int lane = threadIdx.x & 63;
    float w[K];
#pragma unroll
    for (int k = 0; k < K; ++k) w[k] = W[k * HD + lane];
    const float b = bias[lane];
    const bool isb = flag[0] != 0;
    const int wid = (bid << 2) + (threadIdx.x >> 6);
    const int stride = nblk << 2;
    if (isb) {
        const unsigned short* xb = (const unsigned short*)x;
        for (int r = wid; r < N; r += stride) {
            const unsigned short* xr = xb + (size_t)r * K;
            float acc = b;
#pragma unroll
            for (int k = 0; k < K; ++k)
                acc = fmaf(__uint_as_float(((unsigned int)xr[k]) << 16), w[k], acc);
            out[(size_t)r * HD + lane] = acc;
        }
    } else {
        const float* xf = (const float*)x;
        for (int r = wid; r < N; r += stride) {
            const float* xr = xf + (size_t)r * K;
            float acc = b;
#pragma unroll
            for (int k = 0; k < K; ++k) acc = fmaf(xr[k], w[k], acc);
            out[(size_t)r * HD + lane] = acc;
        }
    }
}

__device__ __forceinline__ void place_dev(int gid, const int* __restrict__ e_u2u,
                                          const int* __restrict__ e_t2t,
                                          const int* __restrict__ e_u2t,
                                          const int* __restrict__ e_t2u,
                                          const int* __restrict__ rp, int* __restrict__ fill,
                                          int* __restrict__ colU, int* __restrict__ colT) {
    if (gid >= 4 * NE_) return;
    int r = gid / NE_;
    int e = gid - r * NE_;
    const int* ei;
    int rpo;
    unsigned int tag;
    int* cl;
    switch (r) {
        case 0: ei = e_u2u; rpo = 0;   tag = 0u;          cl = colU; break;
        case 1: ei = e_t2u; rpo = 0;   tag = 0x80000000u; cl = colU; break;
        case 2: ei = e_t2t; rpo = NU_; tag = 0u;          cl = colT; break;
        default: ei = e_u2t; rpo = NU_; tag = 0x80000000u; cl = colT; break;
    }
    int s = ei[e];
    int d = ei[e + NE_];
    int pos = rp[rpo + d] + atomicAdd(&fill[rpo + d], 1);
    cl[pos] = (int)((unsigned int)s | tag);
}

// single-output GEMM: m = fp8((h@W)*sc)  — only w[64] in registers
__device__ __forceinline__ void gemm_one_dev(int bid, int nblk, const float* __restrict__ h,
                                             const float* __restrict__ W,
                                             const float* __restrict__ sc,
                                             unsigned char* __restrict__ m, int N) {
    const int lane = threadIdx.x & 63;
    float w[HD];
#pragma unroll
    for (int k = 0; k < HD; ++k) w[k] = W[k * HD + lane];
    const int wid = (bid << 2) + (threadIdx.x >> 6);
    const int stride = nblk << 2;
    for (int r = wid; r < N; r += stride) {
        const float hv = h[(size_t)r * HD + lane];
        float acc = 0.f;
#pragma unroll
        for (int k = 0; k < HD; ++k) {
            float hk = __shfl(hv, k);
            acc = fmaf(hk, w[k], acc);
        }
        m[(size_t)r * HD + lane] = enc_fp8(acc * sc[r]);
    }
}

__device__ __forceinline__ void gemm_dual_dev(int bid, int nblk, const float* __restrict__ h,
                                              const float* __restrict__ WA,
                                              const float* __restrict__ WB,
                                              const float* __restrict__ scA,
                                              const float* __restrict__ scB,
                                              unsigned char* __restrict__ mA,
                                              unsigned char* __restrict__ mB, int N) {
    const int lane = threadIdx.x & 63;
    float wa[HD], wb[HD];
#pragma unroll
    for (int k = 0; k < HD; ++k) wa[k] = WA[k * HD + lane];
#pragma unroll
    for (int k = 0; k < HD; ++k) wb[k] = WB[k * HD + lane];
    const int wid = (bid << 2) + (threadIdx.x >> 6);
    const int stride = nblk << 2;
    for (int r = wid; r < N; r += stride) {
        const float hv = h[(size_t)r * HD + lane];
        float accA = 0.f, accB = 0.f;
#pragma unroll
        for (int k = 0; k < HD; ++k) {
            float hk = __shfl(hv, k);
            accA = fmaf(hk, wa[k], accA);
            accB = fmaf(hk, wb[k], accB);
        }
        mA[(size_t)r * HD + lane] = enc_fp8(accA * scA[r]);
        mB[(size_t)r * HD + lane] = enc_fp8(accB * scB[r]);
    }
}

// R6-proven gather body: 1 dst/wave, 8 groups of 8 lanes, uint2 (8 fp8) loads,
// 4-slot software pipeline. col tag bit31: 0 -> mA (dA), 1 -> mB (dB).
__device__ __forceinline__ void gather_dev(int blk, const unsigned char* __restrict__ mA,
                                           const unsigned char* __restrict__ mB,
                                           const int* __restrict__ rp,
                                           const int* __restrict__ cA,
                                           const int* __restrict__ cB,
                                           const int* __restrict__ col,
                                           const float* __restrict__ dAv_,
                                           const float* __restrict__ dBv_,
                                           const float* __restrict__ ba,
                                           const float* __restrict__ bb,
                                           float* __restrict__ out, int N) {
    const int lane = threadIdx.x & 63;
    const int grp = lane >> 3;
    const int sub = lane & 7;
    const int d = (blk << 2) + (threadIdx.x >> 6);
    if (d >= N) return;

    const float dA = dAv_[d];
    const float dB = dBv_[d];
    float acc[8] = {0.f, 0.f, 0.f, 0.f, 0.f, 0.f, 0.f, 0.f};

    const uint2 uself = *(const uint2*)(mA + ((size_t)d << 6) + (sub << 3));

    int st = rp[d];
    int cnt = cA[d] + cB[d];
    int done = 0;
    while (done < cnt) {
        int rem = cnt - done;
        if (rem > 64) rem = 64;
        int cw = (lane < rem) ? col[st + done + lane] : 0;
        const int nch = (rem + 7) >> 3;

        uint2 ub0, ub1, ub2, ub3;
        float sc0, sc1, sc2, sc3;

        auto issue = [&](int p, uint2& ub, float& sc) {
            int j = (p << 3) + grp;
            unsigned int c = (unsigned int)__shfl(cw, j);
            const unsigned char* base = (c >> 31) ? mB : mA;
            float sv = (c >> 31) ? dB : dA;
            unsigned int idx = c & 0x7fffffffu;
            sc = (j < rem) ? sv : 0.f;
            ub = *(const uint2*)(base + ((size_t)idx << 6) + (sub << 3));
        };
        auto consume = [&](uint2 u, float s) {
            float f[8];
            dec4_fp8(u.x, f);
            dec4_fp8(u.y, f + 4);
#pragma unroll
            for (int k = 0; k < 8; ++k) acc[k] = fmaf(f[k], s, acc[k]);
        };

        issue(0, ub0, sc0);
        if (nch > 1) issue(1, ub1, sc1);
        if (nch > 2) issue(2, ub2, sc2);
        if (nch > 3) issue(3, ub3, sc3);

        consume(ub0, sc0);
        if (nch > 4) issue(4, ub0, sc0);
        if (nch > 1) consume(ub1, sc1);
        if (nch > 5) issue(5, ub1, sc1);
        if (nch > 2) consume(ub2, sc2);
        if (nch > 6) issue(6, ub2, sc2);
        if (nch > 3) consume(ub3, sc3);
        if (nch > 7) issue(7, ub3, sc3);
        if (nch > 4) consume(ub0, sc0);
        if (nch > 5) consume(ub1, sc1);
        if (nch > 6) consume(ub2, sc2);
        if (nch > 7) consume(ub3, sc3);

        done += rem;
    }

    {
        float f[8];
        dec4_fp8(uself.x, f);
        dec4_fp8(uself.y, f + 4);
        const float s = (grp == 0) ? dA : 0.f;
#pragma unroll
        for (int k = 0; k < 8; ++k) acc[k] = fmaf(f[k], s, acc[k]);
    }

#pragma unroll
    for (int k = 0; k < 8; ++k) {
        acc[k] += __shfl_xor(acc[k], 8);
        acc[k] += __shfl_xor(acc[k], 16);
        acc[k] += __shfl_xor(acc[k], 32);
    }

    if (grp == 0) {
        const int col0 = sub << 3;
        float o[8];
#pragma unroll
        for (int k = 0; k < 8; ++k)
            o[k] = fmaxf(0.5f * (acc[k] + ba[col0 + k] + bb[col0 + k]), 0.f);
        float4 v0 = {o[0], o[1], o[2], o[3]};
        float4 v1 = {o[4], o[5], o[6], o[7]};
        *(float4*)(out + ((size_t)d << 6) + col0) = v0;
        *(float4*)(out + ((size_t)d << 6) + col0 + 4) = v1;
    }
}

// ---------------- fused kernels ----------------
__global__ __launch_bounds__(256) void fused_hist_embed(
    const int* __restrict__ a0, const int* __restrict__ a1, const int* __restrict__ a2,
    const int* __restrict__ a3, const int* __restrict__ a4, const int* __restrict__ a5,
    int* __restrict__ hist, const void* __restrict__ x_user, const void* __restrict__ x_txn,
    const float* __restrict__ Wembu, const float* __restrict__ bembu,
    const float* __restrict__ Wembt, const float* __restrict__ bembt,
    float* __restrict__ hu, float* __restrict__ ht, const int* __restrict__ flag) {
    int b = blockIdx.x;
    if (b < HB) {
        hist_dev(b * 256 + threadIdx.x, a0, a1, a2, a3, a4, a5, hist);
    } else if (b < HB + EU) {
        embed_dev<32>(b - HB, EU, x_user, Wembu, bembu, hu, NU_, flag);
    } else {
        embed_dev<64>(b - HB - EU, ET, x_txn, Wembt, bembt, ht, NT_, flag);
    }
}

// place + layer-0 GEMMs as 4 single-output segments (VGPR ~72, place keeps occupancy)
__global__ __launch_bounds__(256) void fused_place_gemm(
    const int* __restrict__ e_u2u, const int* __restrict__ e_t2t,
    const int* __restrict__ e_u2t, const int* __restrict__ e_t2u,
    const int* __restrict__ rp, int* __restrict__ fill,
    int* __restrict__ colU, int* __restrict__ colT,
    const float* __restrict__ hu, const float* __restrict__ ht,
    const float* __restrict__ W0, const float* __restrict__ Wu2t,
    const float* __restrict__ Wt, const float* __restrict__ Wt2u,
    const float* __restrict__ dinv,
    unsigned char* __restrict__ m_uu, unsigned char* __restrict__ m_ut,
    unsigned char* __restrict__ m_tt, unsigned char* __restrict__ m_tu) {
    int b = blockIdx.x;
    if (b < PB) {
        place_dev(b * 256 + threadIdx.x, e_u2u, e_t2t, e_u2t, e_t2u, rp, fill, colU, colT);
    } else if (b < PB + SG1) {
        gemm_one_dev(b - PB, SG1, hu, W0, dinv + OFF0, m_uu, NU_);
    } else if (b < PB + 2 * SG1) {
        gemm_one_dev(b - PB - SG1, SG1, hu, Wu2t, dinv + OFF4, m_ut, NU_);
    } else if (b < PB + 2 * SG1 + SG2) {
        gemm_one_dev(b - PB - 2 * SG1, SG2, ht, Wt, dinv + OFF1, m_tt, NT_);
    } else {
        gemm_one_dev(b - PB - 2 * SG1 - SG2, SG2, ht, Wt2u, dinv + OFF5, m_tu, NT_);
    }
}

__global__ __launch_bounds__(256) void gemm_dual_both(
    const float* __restrict__ hu, const float* __restrict__ ht,
    const float* __restrict__ W0, const float* __restrict__ Wu2t,
    const float* __restrict__ Wt, const float* __restrict__ Wt2u,
    const float* __restrict__ dinv,
    unsigned char* __restrict__ m_uu, unsigned char* __restrict__ m_ut,
    unsigned char* __restrict__ m_tt, unsigned char* __restrict__ m_tu) {
    int b = blockIdx.x;
    if (b < GU) {
        gemm_dual_dev(b, GU, hu, W0, Wu2t, dinv + OFF0, dinv + OFF4, m_uu, m_ut, NU_);
    } else {
        gemm_dual_dev(b - GU, GT, ht, Wt, Wt2u, dinv + OFF1, dinv + OFF5, m_tt, m_tu, NT_);
    }
}

__global__ __launch_bounds__(256) void gather_both(
    const unsigned char* __restrict__ m_uu, const unsigned char* __restrict__ m_tu,
    const unsigned char* __restrict__ m_tt, const unsigned char* __restrict__ m_ut,
    const int* __restrict__ rp, const int* __restrict__ hist,
    const int* __restrict__ colU, const int* __restrict__ colT,
    const float* __restrict__ dinv,
    const float* __restrict__ bU0, const float* __restrict__ bU1,
    const float* __restrict__ bT0, const float* __restrict__ bT1,
    float* __restrict__ hu, float* __restrict__ ht) {
    int b = blockIdx.x;
    if (b < GBU) {
        gather_dev(b, m_uu, m_tu, rp, hist + OFF0, hist + OFF3, colU,
                   dinv + OFF0, dinv + OFF3, bU0, bU1, hu, NU_);
    } else {
        gather_dev(b - GBU, m_tt, m_ut, rp + NU_, hist + OFF1, hist + OFF2, colT,
                   dinv + OFF1, dinv + OFF2, bT0, bT1, ht, NT_);
    }
}

// ---------------- CSR scan kernels (dinv folded in) ----------------
__global__ __launch_bounds__(256) void scan1m(const int* __restrict__ hist, int* __restrict__ rp,
                                              int* __restrict__ bsums, float* __restrict__ dinv) {
    int b = blockIdx.x, t = threadIdx.x;
    int r, lb, n, rpbase, oA, oB;
    if (b < NBU) { r = 0; lb = b;       n = NU_; rpbase = 0;   oA = OFF0; oB = OFF3; }
    else         { r = 1; lb = b - NBU; n = NT_; rpbase = NU_; oA = OFF1; oB = OFF2; }
    int i = lb * 256 + t;
    int hA = (i < n) ? hist[oA + i] : 0;
    int hB = (i < n) ? hist[oB + i] : 0;
    if (i < n) {
        dinv[oA + i] = rsqrtf((float)hA + 1.0f);                       // self-loop type
        dinv[oB + i] = (hB > 0) ? rsqrtf((float)hB) : 0.f;             // bipartite dst
    }
    int v = hA + hB;
    __shared__ int s[256];
    s[t] = v;
    __syncthreads();
    for (int off = 1; off < 256; off <<= 1) {
        int x = (t >= off) ? s[t - off] : 0;
        __syncthreads();
        s[t] += x;
        __syncthreads();
    }
    if (i < n) rp[rpbase + i] = s[t] - v;
    if (t == 255) bsums[r * 1024 + lb] = s[255];
}

__global__ __launch_bounds__(1024) void scan2m(int* __restrict__ bsums) {
    int r = blockIdx.x, t = threadIdx.x;
    const int nb = r ? NBT : NBU;
    int v = (t < nb) ? bsums[r * 1024 + t] : 0;
    __shared__ int s[1024];
    s[t] = v;
    __syncthreads();
    for (int off = 1; off < 1024; off <<= 1) {
        int x = (t >= off) ? s[t - off] : 0;
        __syncthreads();
        s[t] += x;
        __syncthreads();
    }
    if (t < nb) bsums[r * 1024 + t] = s[t] - v;
}

// scan3m also computes dinv for the two src-hist regions (same 300k index space)
__global__ void scan3m(int* __restrict__ rp, const int* __restrict__ bsums,
                       const int* __restrict__ hist, float* __restrict__ dinv) {
    int gid = blockIdx.x * blockDim.x + threadIdx.x;
    if (gid >= RPT2) return;
    int r = (gid < NU_) ? 0 : 1;
    int base = r ? NU_ : 0;
    int lb = (gid - base) >> 8;
    rp[gid] += bsums[r * 1024 + lb];
    int si = r ? (OFF5 + gid - NU_) : (OFF4 + gid);
    int h = hist[si];
    dinv[si] = (h > 0) ? rsqrtf((float)h) : 0.f;
}

// ---------------- readout ----------------
__global__ __launch_bounds__(256) void colmean_both(const float* __restrict__ hu,
                                                    const float* __restrict__ ht,
                                                    float* __restrict__ gsum) {
    const bool isU = blockIdx.x < 512;
    const float* h = isU ? hu : ht;
    const int n = isU ? NU_ : NT_;
    const float scale = isU ? 0.5f / NU_ : 0.5f / NT_;
    const int blk = isU ? blockIdx.x : blockIdx.x - 512;
    const int lane = threadIdx.x & 63;
    const int w = threadIdx.x >> 6;
    float s = 0.f;
    for (int r = blk * 4 + w; r < n; r += 512 * 4)
        s += h[(size_t)r * HD + lane];
    __shared__ float red[256];
    red[threadIdx.x] = s;
    __syncthreads();
    if (threadIdx.x < 64) {
        float t = red[threadIdx.x] + red[64 + threadIdx.x] + red[128 + threadIdx.x] +
                  red[192 + threadIdx.x];
        atomicAdd(&gsum[lane], t * scale);
    }
}

__global__ void head(const float* __restrict__ g, const float* __restrict__ W1,
                     const float* __restrict__ b1, const float* __restrict__ W2,
                     const float* __restrict__ b2, const int* __restrict__ flag,
                     void* __restrict__ out) {
    const int c = threadIdx.x;
    float x = b1[c];
    for (int k = 0; k < HD; ++k) x = fmaf(g[k], W1[k * HD + c], x);
    x = fmaxf(x, 0.f);
    float t = x * W2[c];
    for (int off = 32; off; off >>= 1) t += __shfl_down(t, off);
    if (c == 0) {
        float z = t + b2[0];
        float s = 1.f / (1.f + expf(-z));
        if (flag[0]) *(__hip_bfloat16*)out = __float2bfloat16(s);
        else *(float*)out = s;
    }
}

extern "C" void kernel_launch(void* const* d_in, const int* in_sizes, int n_in,
                              void* d_out, int out_size, void* d_ws, size_t ws_size,
                              hipStream_t stream) {
    const void* x_user = d_in[0];
    const void* x_txn  = d_in[1];
    const int* ei_u2u = (const int*)d_in[2];
    const int* ei_t2t = (const int*)d_in[3];
    const int* ei_u2t = (const int*)d_in[4];
    const int* ei_t2u = (const int*)d_in[5];

    // ---- workspace layout ----
    float* ws = (float*)d_ws;
    float* hu = ws;                                   // NU*64 f32
    float* ht = hu + (size_t)NU_ * HD;                // NT*64 f32
    float* dinv = ht + (size_t)NT_ * HD;              // HTOT
    float* wts = dinv + HTOT;                         // 60432 (padded)
    float* gsum = wts + 60432;                        // 64
    unsigned char* m_uu = (unsigned char*)(gsum + 64);  // NU*64 fp8
    unsigned char* m_ut = m_uu + (size_t)NU_ * HD;
    unsigned char* m_tt = m_ut + (size_t)NU_ * HD;
    unsigned char* m_tu = m_tt + (size_t)NT_ * HD;
    int* hist = (int*)(m_tu + (size_t)NT_ * HD);      // HTOT
    int* fill = hist + HTOT;                          // RPT2
    int* rp   = fill + RPT2;                          // RPT2
    int* bsums = rp + RPT2;                           // 2048
    int* colU = bsums + 2048;                         // 2M
    int* colT = colU + 2 * NE_;                       // 2M
    int* dflag = colT + 2 * NE_;                      // 1

    // fp32 weight sub-pointers
    float* Wembu = wts;              // 2048
    float* bembu = Wembu + 2048;     // 64
    float* Wembt = bembu + 64;       // 4096
    float* bembt = Wembt + 4096;     // 64
    float* convWf = bembt + 64;      // 49152
    float* convbf = convWf + 49152;  // 768
    float* W1f = convbf + 768;       // 4096
    float* b1f = W1f + 4096;         // 64
    float* W2f = b1f + 64;           // 64
    float* b2f = W2f + 64;           // 1

    hipMemsetAsync(hist, 0, (size_t)(HTOT + RPT2) * sizeof(int), stream);

    detect_dtype<<<1, 256, 0, stream>>>((const unsigned short*)x_user, dflag, 2048);
    {
        Ptr10 p;
        for (int k = 0; k < 10; ++k) p.p[k] = d_in[6 + k];
        cvt_weights<<<(60417 + 255) / 256, 256, 0, stream>>>(p, wts, gsum, dflag);
    }

    // ---- fused: histograms + embedding GEMMs ----
    fused_hist_embed<<<HB + EU + ET, 256, 0, stream>>>(
        ei_u2u + NE_, ei_t2t + NE_, ei_u2t + NE_, ei_t2u + NE_, ei_u2t, ei_t2u, hist,
        x_user, x_txn, Wembu, bembu, Wembt, bembt, hu, ht, dflag);

    scan1m<<<NBTOT2, 256, 0, stream>>>(hist, rp, bsums, dinv);
    scan2m<<<2, 1024, 0, stream>>>(bsums);
    scan3m<<<(RPT2 + 255) / 256, 256, 0, stream>>>(rp, bsums, hist, dinv);

    const float* W0l0   = convWf + 0 * HD * HD;
    const float* Wtl0   = convWf + 1 * HD * HD;
    const float* Wu2tl0 = convWf + 2 * HD * HD;
    const float* Wt2ul0 = convWf + 3 * HD * HD;

    // ---- fused: CSR placement + layer-0 GEMMs (low-VGPR single segments) ----
    fused_place_gemm<<<PB + 2 * SG1 + 2 * SG2, 256, 0, stream>>>(
        ei_u2u, ei_t2t, ei_u2t, ei_t2u, rp, fill, colU, colT,
        hu, ht, W0l0, Wu2tl0, Wtl0, Wt2ul0, dinv, m_uu, m_ut, m_tt, m_tu);

    for (int l = 0; l < NL; ++l) {
        const float* B0   = convbf + ((size_t)l * 4 + 0) * HD;
        const float* Bt   = convbf + ((size_t)l * 4 + 1) * HD;
        const float* Bu2t = convbf + ((size_t)l * 4 + 2) * HD;
        const float* Bt2u = convbf + ((size_t)l * 4 + 3) * HD;

        if (l > 0) {
            const float* W0   = convWf + ((size_t)l * 4 + 0) * HD * HD;
            const float* Wt   = convWf + ((size_t)l * 4 + 1) * HD * HD;
            const float* Wu2t = convWf + ((size_t)l * 4 + 2) * HD * HD;
            const float* Wt2u = convWf + ((size_t)l * 4 + 3) * HD * HD;
            gemm_dual_both<<<GU + GT, 256, 0, stream>>>(hu, ht, W0, Wu2t, Wt, Wt2u, dinv,
                                                        m_uu, m_ut, m_tt, m_tu);
        }

        gather_both<<<GBU + GBT, 256, 0, stream>>>(m_uu, m_tu, m_tt, m_ut,
                                                   rp, hist, colU, colT, dinv,
                                                   B0, Bt2u, Bt, Bu2t, hu, ht);
    }

    // ---- readout ----
    colmean_both<<<1024, 256, 0, stream>>>(hu, ht, gsum);
    head<<<1, 64, 0, stream>>>(gsum, W1f, b1f, W2f, b2f, dflag, d_out);
}

// Round 10
// 1890.808 us; speedup vs baseline: 1.0875x; 1.0875x over previous
//
#include <hip/hip_runtime.h>
#include <hip/hip_bf16.h>
#include <hip/hip_fp8.h>

#define NU_ 100000
#define NT_ 200000
#define NE_ 1000000
#define HD  64
#define NL  3

// hist/dinv region offsets (node-keyed arrays)
#define OFF0 0                   // u2u dst (NU)  [selfloop]
#define OFF1 (NU_)               // t2t dst (NT)  [selfloop]
#define OFF2 (NU_ + NT_)         // u2t dst (NT)
#define OFF3 (NU_ + 2 * NT_)     // t2u dst (NU)
#define OFF4 (2 * NU_ + 2 * NT_) // u2t src (NU)
#define OFF5 (3 * NU_ + 2 * NT_) // t2u src (NT)
#define HTOT (3 * NU_ + 3 * NT_) // 900k
#define RPT2 (NU_ + NT_)         // merged rp/fill size (300k)

// merged scan partition (256/block)
#define NBU 391
#define NBT 782
#define NBTOT2 (NBU + NBT)

// fused grids
#define HB  23438          // ceil(6M/256) hist blocks
#define EU  4096           // embed user blocks
#define ET  8192           // embed txn blocks
#define GU  4096           // gemm_dual user blocks
#define GT  8192           // gemm_dual txn blocks
#define GBU 25000          // ceil(NU/4) gather blocks (user)
#define GBT 50000          // ceil(NT/4) gather blocks (txn)

typedef float floatx2 __attribute__((ext_vector_type(2)));

// ---------------- fp8 helpers ----------------
__device__ __forceinline__ unsigned char enc_fp8(float v) {
    return (unsigned char)__hip_cvt_float_to_fp8(v, __HIP_SATFINITE, __HIP_E4M3);
}

__device__ __forceinline__ float dec1_fp8(unsigned int u) {
    int e = (u >> 3) & 15;
    int m = u & 7;
    int mant = m | (e ? 8 : 0);
    if (u & 0x80) mant = -mant;
    int ex = (e ? e : 1) - 10;
    return (float)mant * __uint_as_float((unsigned int)(ex + 127) << 23);
}

__device__ __forceinline__ void dec4_fp8(unsigned int u, float* f) {
#if __has_builtin(__builtin_amdgcn_cvt_pk_f32_fp8)
    floatx2 lo = __builtin_amdgcn_cvt_pk_f32_fp8((int)u, false);
    floatx2 hi = __builtin_amdgcn_cvt_pk_f32_fp8((int)u, true);
    f[0] = lo.x; f[1] = lo.y; f[2] = hi.x; f[3] = hi.y;
#else
    f[0] = dec1_fp8(u & 0xff);
    f[1] = dec1_fp8((u >> 8) & 0xff);
    f[2] = dec1_fp8((u >> 16) & 0xff);
    f[3] = dec1_fp8((u >> 24) & 0xff);
#endif
}

// ---------------- dtype detection ----------------
__global__ void detect_dtype(const unsigned short* __restrict__ x, int* __restrict__ flag, int n) {
    __shared__ int s_big;
    if (threadIdx.x == 0) s_big = 0;
    __syncthreads();
    int big = 0;
    for (int i = threadIdx.x; i < n; i += blockDim.x) {
        float v = __uint_as_float(((unsigned int)x[i]) << 16);
        if (!(fabsf(v) < 1.0e4f)) big = 1;
    }
    if (big) atomicAdd(&s_big, 1);
    __syncthreads();
    if (threadIdx.x == 0) flag[0] = (s_big > 0) ? 0 : 1;
}

// ---------------- fused weight conversion (+ gsum zero) ----------------
struct Ptr10 { const void* p[10]; };

__global__ void cvt_weights(Ptr10 src, float* __restrict__ dst, float* __restrict__ gsum,
                            const int* __restrict__ flag) {
    const int c[11] = {0, 2048, 2112, 6208, 6272, 55424, 56192, 60288, 60352, 60416, 60417};
    int i = blockIdx.x * blockDim.x + threadIdx.x;
    if (i < 64) gsum[i] = 0.f;
    if (i >= 60417) return;
    int r = 0;
#pragma unroll
    for (int k = 1; k < 10; ++k)
        if (i >= c[k]) r = k;
    int e = i - c[r];
    if (flag[0]) {
        unsigned short u = ((const unsigned short*)src.p[r])[e];
        dst[i] = __uint_as_float(((unsigned int)u) << 16);
    } else {
        dst[i] = ((const float*)src.p[r])[e];
    }
}

// ---------------- device bodies ----------------
__device__ __forceinline__ void hist_dev(int gid, const int* __restrict__ a0,
                                         const int* __restrict__ a1, const int* __restrict__ a2,
                                         const int* __restrict__ a3, const int* __restrict__ a4,
                                         const int* __restrict__ a5, int* __restrict__ hist) {
    if (gid >= 6 * NE_) return;
    int r = gid / NE_;
    int e = gid - r * NE_;
    const int* a;
    int base;
    switch (r) {
        case 0: a = a0; base = OFF0; break;
        case 1: a = a1; base = OFF1; break;
        case 2: a = a2; base = OFF2; break;
        case 3: a = a3; base = OFF3; break;
        case 4: a = a4; base = OFF4; break;
        default: a = a5; base = OFF5; break;
    }
    atomicAdd(&hist[base + a[e]], 1);
}

template <int K>
__device__ __forceinline__ void embed_dev(int bid, int nblk, const void* __restrict__ x,
                                          const float* __restrict__ W,
                                          const float* __restrict__ bias,
                                          float* __restrict__ out, int N,
                                          const int* __restrict__ flag) {
    const int lane = threadIdx.x & 63;
    float w[K];
#pragma unroll
    for (int k = 0; k < K; ++k) w[k] = W[k * HD + lane];
    const float b = bias[lane];
    const bool isb = flag[0] != 0;
    const int wid = (bid << 2) + (threadIdx.x >> 6);
    const int stride = nblk << 2;
    if (isb) {
        const unsigned short* xb = (const unsigned short*)x;
        for (int r = wid; r < N; r += stride) {
            const unsigned short* xr = xb + (size_t)r * K;
            float acc = b;
#pragma unroll
            for (int k = 0; k < K; ++k)
                acc = fmaf(__uint_as_float(((unsigned int)xr[k]) << 16), w[k], acc);
            out[(size_t)r * HD + lane] = acc;
        }
    } else {
        const float* xf = (const float*)x;
        for (int r = wid; r < N; r += stride) {
            const float* xr = xf + (size_t)r * K;
            float acc = b;
#pragma unroll
            for (int k = 0; k < K; ++k) acc = fmaf(xr[k], w[k], acc);
            out[(size_t)r * HD + lane] = acc;
        }
    }
}

__device__ __forceinline__ void gemm_dual_dev(int bid, int nblk, const float* __restrict__ h,
                                              const float* __restrict__ WA,
                                              const float* __restrict__ WB,
                                              const float* __restrict__ scA,
                                              const float* __restrict__ scB,
                                              unsigned char* __restrict__ mA,
                                              unsigned char* __restrict__ mB, int N) {
    const int lane = threadIdx.x & 63;
    float wa[HD], wb[HD];
#pragma unroll
    for (int k = 0; k < HD; ++k) wa[k] = WA[k * HD + lane];
#pragma unroll
    for (int k = 0; k < HD; ++k) wb[k] = WB[k * HD + lane];
    const int wid = (bid << 2) + (threadIdx.x >> 6);
    const int stride = nblk << 2;
    for (int r = wid; r < N; r += stride) {
        const float hv = h[(size_t)r * HD + lane];
        float accA = 0.f, accB = 0.f;
#pragma unroll
        for (int k = 0; k < HD; ++k) {
            float hk = __shfl(hv, k);
            accA = fmaf(hk, wa[k], accA);
            accB = fmaf(hk, wb[k], accB);
        }
        mA[(size_t)r * HD + lane] = enc_fp8(accA * scA[r]);
        mB[(size_t)r * HD + lane] = enc_fp8(accB * scB[r]);
    }
}

// R6-proven gather body + packed int4 metadata {rp, cnt, dA, dB}.
__device__ __forceinline__ void gather_dev(int blk, const unsigned char* __restrict__ mA,
                                           const unsigned char* __restrict__ mB,
                                           const int4* __restrict__ meta,
                                           const int* __restrict__ col,
                                           const float* __restrict__ ba,
                                           const float* __restrict__ bb,
                                           float* __restrict__ out, int N) {
    const int lane = threadIdx.x & 63;
    const int grp = lane >> 3;
    const int sub = lane & 7;
    const int d = (blk << 2) + (threadIdx.x >> 6);
    if (d >= N) return;

    const int4 mt = meta[d];
    const int st = mt.x;
    const int cnt = mt.y;
    const float dA = __int_as_float(mt.z);
    const float dB = __int_as_float(mt.w);
    float acc[8] = {0.f, 0.f, 0.f, 0.f, 0.f, 0.f, 0.f, 0.f};

    const uint2 uself = *(const uint2*)(mA + ((size_t)d << 6) + (sub << 3));

    int done = 0;
    while (done < cnt) {
        int rem = cnt - done;
        if (rem > 64) rem = 64;
        int cw = (lane < rem) ? col[st + done + lane] : 0;
        const int nch = (rem + 7) >> 3;

        uint2 ub0, ub1, ub2, ub3;
        float sc0, sc1, sc2, sc3;

        auto issue = [&](int p, uint2& ub, float& sc) {
            int j = (p << 3) + grp;
            unsigned int c = (unsigned int)__shfl(cw, j);
            const unsigned char* base = (c >> 31) ? mB : mA;
            float sv = (c >> 31) ? dB : dA;
            unsigned int idx = c & 0x7fffffffu;
            sc = (j < rem) ? sv : 0.f;
            ub = *(const uint2*)(base + ((size_t)idx << 6) + (sub << 3));
        };
        auto consume = [&](uint2 u, float s) {
            float f[8];
            dec4_fp8(u.x, f);
            dec4_fp8(u.y, f + 4);
#pragma unroll
            for (int k = 0; k < 8; ++k) acc[k] = fmaf(f[k], s, acc[k]);
        };

        issue(0, ub0, sc0);
        if (nch > 1) issue(1, ub1, sc1);
        if (nch > 2) issue(2, ub2, sc2);
        if (nch > 3) issue(3, ub3, sc3);

        consume(ub0, sc0);
        if (nch > 4) issue(4, ub0, sc0);
        if (nch > 1) consume(ub1, sc1);
        if (nch > 5) issue(5, ub1, sc1);
        if (nch > 2) consume(ub2, sc2);
        if (nch > 6) issue(6, ub2, sc2);
        if (nch > 3) consume(ub3, sc3);
        if (nch > 7) issue(7, ub3, sc3);
        if (nch > 4) consume(ub0, sc0);
        if (nch > 5) consume(ub1, sc1);
        if (nch > 6) consume(ub2, sc2);
        if (nch > 7) consume(ub3, sc3);

        done += rem;
    }

    {
        float f[8];
        dec4_fp8(uself.x, f);
        dec4_fp8(uself.y, f + 4);
        const float s = (grp == 0) ? dA : 0.f;
#pragma unroll
        for (int k = 0; k < 8; ++k) acc[k] = fmaf(f[k], s, acc[k]);
    }

#pragma unroll
    for (int k = 0; k < 8; ++k) {
        acc[k] += __shfl_xor(acc[k], 8);
        acc[k] += __shfl_xor(acc[k], 16);
        acc[k] += __shfl_xor(acc[k], 32);
    }

    if (grp == 0) {
        const int col0 = sub << 3;
        float o[8];
#pragma unroll
        for (int k = 0; k < 8; ++k)
            o[k] = fmaxf(0.5f * (acc[k] + ba[col0 + k] + bb[col0 + k]), 0.f);
        float4 v0 = {o[0], o[1], o[2], o[3]};
        float4 v1 = {o[4], o[5], o[6], o[7]};
        *(float4*)(out + ((size_t)d << 6) + col0) = v0;
        *(float4*)(out + ((size_t)d << 6) + col0 + 4) = v1;
    }
}

// ---------------- fused kernels ----------------
__global__ __launch_bounds__(256) void fused_hist_embed(
    const int* __restrict__ a0, const int* __restrict__ a1, const int* __restrict__ a2,
    const int* __restrict__ a3, const int* __restrict__ a4, const int* __restrict__ a5,
    int* __restrict__ hist, const void* __restrict__ x_user, const void* __restrict__ x_txn,
    const float* __restrict__ Wembu, const float* __restrict__ bembu,
    const float* __restrict__ Wembt, const float* __restrict__ bembt,
    float* __restrict__ hu, float* __restrict__ ht, const int* __restrict__ flag) {
    int b = blockIdx.x;
    if (b < HB) {
        hist_dev(b * 256 + threadIdx.x, a0, a1, a2, a3, a4, a5, hist);
    } else if (b < HB + EU) {
        embed_dev<32>(b - HB, EU, x_user, Wembu, bembu, hu, NU_, flag);
    } else {
        embed_dev<64>(b - HB - EU, ET, x_txn, Wembt, bembt, ht, NT_, flag);
    }
}

// standalone CSR placement (R6-proven: 8 VGPR, high occupancy)
__global__ __launch_bounds__(256) void place4m(const int* __restrict__ e_u2u,
                                               const int* __restrict__ e_t2t,
                                               const int* __restrict__ e_u2t,
                                               const int* __restrict__ e_t2u,
                                               const int* __restrict__ rp, int* __restrict__ fill,
                                               int* __restrict__ colU, int* __restrict__ colT) {
    int gid = blockIdx.x * 256 + threadIdx.x;
    if (gid >= 4 * NE_) return;
    int r = gid / NE_;
    int e = gid - r * NE_;
    const int* ei;
    int rpo;
    unsigned int tag;
    int* cl;
    switch (r) {
        case 0: ei = e_u2u; rpo = 0;   tag = 0u;          cl = colU; break;
        case 1: ei = e_t2u; rpo = 0;   tag = 0x80000000u; cl = colU; break;
        case 2: ei = e_t2t; rpo = NU_; tag = 0u;          cl = colT; break;
        default: ei = e_u2t; rpo = NU_; tag = 0x80000000u; cl = colT; break;
    }
    int s = ei[e];
    int d = ei[e + NE_];
    int pos = rp[rpo + d] + atomicAdd(&fill[rpo + d], 1);
    cl[pos] = (int)((unsigned int)s | tag);
}

__global__ __launch_bounds__(256) void gemm_dual_both(
    const float* __restrict__ hu, const float* __restrict__ ht,
    const float* __restrict__ W0, const float* __restrict__ Wu2t,
    const float* __restrict__ Wt, const float* __restrict__ Wt2u,
    const float* __restrict__ dinv,
    unsigned char* __restrict__ m_uu, unsigned char* __restrict__ m_ut,
    unsigned char* __restrict__ m_tt, unsigned char* __restrict__ m_tu) {
    int b = blockIdx.x;
    if (b < GU) {
        gemm_dual_dev(b, GU, hu, W0, Wu2t, dinv + OFF0, dinv + OFF4, m_uu, m_ut, NU_);
    } else {
        gemm_dual_dev(b - GU, GT, ht, Wt, Wt2u, dinv + OFF1, dinv + OFF5, m_tt, m_tu, NT_);
    }
}

__global__ __launch_bounds__(256) void gather_both(
    const unsigned char* __restrict__ m_uu, const unsigned char* __restrict__ m_tu,
    const unsigned char* __restrict__ m_tt, const unsigned char* __restrict__ m_ut,
    const int4* __restrict__ meta,
    const int* __restrict__ colU, const int* __restrict__ colT,
    const float* __restrict__ bU0, const float* __restrict__ bU1,
    const float* __restrict__ bT0, const float* __restrict__ bT1,
    float* __restrict__ hu, float* __restrict__ ht) {
    int b = blockIdx.x;
    if (b < GBU) {
        gather_dev(b, m_uu, m_tu, meta, colU, bU0, bU1, hu, NU_);
    } else {
        gather_dev(b - GBU, m_tt, m_ut, meta + NU_, colT, bT0, bT1, ht, NT_);
    }
}

// ---------------- CSR scan kernels (dinv folded in) ----------------
__global__ __launch_bounds__(256) void scan1m(const int* __restrict__ hist, int* __restrict__ rp,
                                              int* __restrict__ bsums, float* __restrict__ dinv) {
    int b = blockIdx.x, t = threadIdx.x;
    int r, lb, n, rpbase, oA, oB;
    if (b < NBU) { r = 0; lb = b;       n = NU_; rpbase = 0;   oA = OFF0; oB = OFF3; }
    else         { r = 1; lb = b - NBU; n = NT_; rpbase = NU_; oA = OFF1; oB = OFF2; }
    int i = lb * 256 + t;
    int hA = (i < n) ? hist[oA + i] : 0;
    int hB = (i < n) ? hist[oB + i] : 0;
    if (i < n) {
        dinv[oA + i] = rsqrtf((float)hA + 1.0f);                       // self-loop type
        dinv[oB + i] = (hB > 0) ? rsqrtf((float)hB) : 0.f;             // bipartite dst
    }
    int v = hA + hB;
    __shared__ int s[256];
    s[t] = v;
    __syncthreads();
    for (int off = 1; off < 256; off <<= 1) {
        int x = (t >= off) ? s[t - off] : 0;
        __syncthreads();
        s[t] += x;
        __syncthreads();
    }
    if (i < n) rp[rpbase + i] = s[t] - v;
    if (t == 255) bsums[r * 1024 + lb] = s[255];
}

__global__ __launch_bounds__(1024) void scan2m(int* __restrict__ bsums) {
    int r = blockIdx.x, t = threadIdx.x;
    const int nb = r ? NBT : NBU;
    int v = (t < nb) ? bsums[r * 1024 + t] : 0;
    __shared__ int s[1024];
    s[t] = v;
    __syncthreads();
    for (int off = 1; off < 1024; off <<= 1) {
        int x = (t >= off) ? s[t - off] : 0;
        __syncthreads();
        s[t] += x;
        __syncthreads();
    }
    if (t < nb) bsums[r * 1024 + t] = s[t] - v;
}

// scan3m: finalize rp, src dinv, and pack gather metadata {rp, cnt, dA, dB}
__global__ void scan3m(int* __restrict__ rp, const int* __restrict__ bsums,
                       const int* __restrict__ hist, float* __restrict__ dinv,
                       int4* __restrict__ meta) {
    int gid = blockIdx.x * blockDim.x + threadIdx.x;
    if (gid >= RPT2) return;
    int r = (gid < NU_) ? 0 : 1;
    int base = r ? NU_ : 0;
    int lb = (gid - base) >> 8;
    int rpf = rp[gid] + bsums[r * 1024 + lb];
    rp[gid] = rpf;
    // src dinv (for GEMM scaling)
    int si = r ? (OFF5 + gid - NU_) : (OFF4 + gid);
    int h = hist[si];
    dinv[si] = (h > 0) ? rsqrtf((float)h) : 0.f;
    // packed gather meta
    int oA = r ? (OFF1 + gid - NU_) : (OFF0 + gid);
    int oB = r ? (OFF2 + gid - NU_) : (OFF3 + gid);
    int hA = hist[oA];
    int hB = hist[oB];
    float dA = rsqrtf((float)hA + 1.0f);
    float dB = (hB > 0) ? rsqrtf((float)hB) : 0.f;
    int4 mt;
    mt.x = rpf;
    mt.y = hA + hB;
    mt.z = __float_as_int(dA);
    mt.w = __float_as_int(dB);
    meta[gid] = mt;
}

// ---------------- readout ----------------
__global__ __launch_bounds__(256) void colmean_both(const float* __restrict__ hu,
                                                    const float* __restrict__ ht,
                                                    float* __restrict__ gsum) {
    const bool isU = blockIdx.x < 512;
    const float* h = isU ? hu : ht;
    const int n = isU ? NU_ : NT_;
    const float scale = isU ? 0.5f / NU_ : 0.5f / NT_;
    const int blk = isU ? blockIdx.x : blockIdx.x - 512;
    const int lane = threadIdx.x & 63;
    const int w = threadIdx.x >> 6;
    float s = 0.f;
    for (int r = blk * 4 + w; r < n; r += 512 * 4)
        s += h[(size_t)r * HD + lane];
    __shared__ float red[256];
    red[threadIdx.x] = s;
    __syncthreads();
    if (threadIdx.x < 64) {
        float t = red[threadIdx.x] + red[64 + threadIdx.x] + red[128 + threadIdx.x] +
                  red[192 + threadIdx.x];
        atomicAdd(&gsum[lane], t * scale);
    }
}

__global__ void head(const float* __restrict__ g, const float* __restrict__ W1,
                     const float* __restrict__ b1, const float* __restrict__ W2,
                     const float* __restrict__ b2, const int* __restrict__ flag,
                     void* __restrict__ out) {
    const int c = threadIdx.x;
    float x = b1[c];
    for (int k = 0; k < HD; ++k) x = fmaf(g[k], W1[k * HD + c], x);
    x = fmaxf(x, 0.f);
    float t = x * W2[c];
    for (int off = 32; off; off >>= 1) t += __shfl_down(t, off);
    if (c == 0) {
        float z = t + b2[0];
        float s = 1.f / (1.f + expf(-z));
        if (flag[0]) *(__hip_bfloat16*)out = __float2bfloat16(s);
        else *(float*)out = s;
    }
}

extern "C" void kernel_launch(void* const* d_in, const int* in_sizes, int n_in,
                              void* d_out, int out_size, void* d_ws, size_t ws_size,
                              hipStream_t stream) {
    const void* x_user = d_in[0];
    const void* x_txn  = d_in[1];
    const int* ei_u2u = (const int*)d_in[2];
    const int* ei_t2t = (const int*)d_in[3];
    const int* ei_u2t = (const int*)d_in[4];
    const int* ei_t2u = (const int*)d_in[5];

    // ---- workspace layout ----
    float* ws = (float*)d_ws;
    float* hu = ws;                                   // NU*64 f32
    float* ht = hu + (size_t)NU_ * HD;                // NT*64 f32
    float* dinv = ht + (size_t)NT_ * HD;              // HTOT
    float* wts = dinv + HTOT;                         // 60432 (padded)
    float* gsum = wts + 60432;                        // 64
    unsigned char* m_uu = (unsigned char*)(gsum + 64);  // NU*64 fp8
    unsigned char* m_ut = m_uu + (size_t)NU_ * HD;
    unsigned char* m_tt = m_ut + (size_t)NU_ * HD;
    unsigned char* m_tu = m_tt + (size_t)NT_ * HD;
    int* hist = (int*)(m_tu + (size_t)NT_ * HD);      // HTOT
    int* fill = hist + HTOT;                          // RPT2
    int* rp   = fill + RPT2;                          // RPT2
    int* bsums = rp + RPT2;                           // 2048
    int* colU = bsums + 2048;                         // 2M
    int* colT = colU + 2 * NE_;                       // 2M
    int4* meta = (int4*)(colT + 2 * NE_);             // RPT2 (16B each)
    int* dflag = (int*)(meta + RPT2);                 // 1

    // fp32 weight sub-pointers
    float* Wembu = wts;              // 2048
    float* bembu = Wembu + 2048;     // 64
    float* Wembt = bembu + 64;       // 4096
    float* bembt = Wembt + 4096;     // 64
    float* convWf = bembt + 64;      // 49152
    float* convbf = convWf + 49152;  // 768
    float* W1f = convbf + 768;       // 4096
    float* b1f = W1f + 4096;         // 64
    float* W2f = b1f + 64;           // 64
    float* b2f = W2f + 64;           // 1

    hipMemsetAsync(hist, 0, (size_t)(HTOT + RPT2) * sizeof(int), stream);

    detect_dtype<<<1, 256, 0, stream>>>((const unsigned short*)x_user, dflag, 2048);
    {
        Ptr10 p;
        for (int k = 0; k < 10; ++k) p.p[k] = d_in[6 + k];
        cvt_weights<<<(60417 + 255) / 256, 256, 0, stream>>>(p, wts, gsum, dflag);
    }

    // ---- fused: histograms + embedding GEMMs ----
    fused_hist_embed<<<HB + EU + ET, 256, 0, stream>>>(
        ei_u2u + NE_, ei_t2t + NE_, ei_u2t + NE_, ei_t2u + NE_, ei_u2t, ei_t2u, hist,
        x_user, x_txn, Wembu, bembu, Wembt, bembt, hu, ht, dflag);

    scan1m<<<NBTOT2, 256, 0, stream>>>(hist, rp, bsums, dinv);
    scan2m<<<2, 1024, 0, stream>>>(bsums);
    scan3m<<<(RPT2 + 255) / 256, 256, 0, stream>>>(rp, bsums, hist, dinv, meta);

    // ---- standalone CSR placement (low-VGPR, high occupancy) ----
    place4m<<<(4 * NE_ + 255) / 256, 256, 0, stream>>>(ei_u2u, ei_t2t, ei_u2t, ei_t2u,
                                                       rp, fill, colU, colT);

    for (int l = 0; l < NL; ++l) {
        const float* W0   = convWf + ((size_t)l * 4 + 0) * HD * HD;
        const float* Wt   = convWf + ((size_t)l * 4 + 1) * HD * HD;
        const float* Wu2t = convWf + ((size_t)l * 4 + 2) * HD * HD;
        const float* Wt2u = convWf + ((size_t)l * 4 + 3) * HD * HD;
        const float* B0   = convbf + ((size_t)l * 4 + 0) * HD;
        const float* Bt   = convbf + ((size_t)l * 4 + 1) * HD;
        const float* Bu2t = convbf + ((size_t)l * 4 + 2) * HD;
        const float* Bt2u = convbf + ((size_t)l * 4 + 3) * HD;

        gemm_dual_both<<<GU + GT, 256, 0, stream>>>(hu, ht, W0, Wu2t, Wt, Wt2u, dinv,
                                                    m_uu, m_ut, m_tt, m_tu);

        gather_both<<<GBU + GBT, 256, 0, stream>>>(m_uu, m_tu, m_tt, m_ut,
                                                   meta, colU, colT,
                                                   B0, Bt2u, Bt, Bu2t, hu, ht);
    }

    // ---- readout ----
    colmean_both<<<1024, 256, 0, stream>>>(hu, ht, gsum);
    head<<<1, 64, 0, stream>>>(gsum, W1f, b1f, W2f, b2f, dflag, d_out);
}